// Round 11
// baseline (752.190 us; speedup 1.0000x reference)
//
#include <hip/hip_runtime.h>
#include <math.h>

typedef _Float16 h8f16 __attribute__((ext_vector_type(8)));
typedef _Float16 h2f16 __attribute__((ext_vector_type(2)));
typedef float f32x4 __attribute__((ext_vector_type(4)));

#define MFMA16(a, b, c) __builtin_amdgcn_mfma_f32_16x16x32_f16((a), (b), (c), 0, 0, 0)

__device__ __forceinline__ float silu_f(float v) {
    return v * __builtin_amdgcn_rcpf(1.0f + __expf(-v));
}

// ---------------------------------------------------------------------------
// z0 + Wc precompute. grid 2049 x 128 threads.
//  blocks 0..2047: z0[b] = (past[b,0,:] @ xw.T + xb) @ zw.T + zb   (f32 exact)
//  block  2048   : Wc = W1b @ xproj_w (128x32), b1t = b1 + W1b@xb + W1a@ln_b
// ---------------------------------------------------------------------------
__global__ __launch_bounds__(128) void z0wc_kernel(
    const float* __restrict__ past,
    const float* __restrict__ xw, const float* __restrict__ xb,
    const float* __restrict__ zw, const float* __restrict__ zb,
    const float* __restrict__ w1, const float* __restrict__ lnb,
    const float* __restrict__ b1,
    float* __restrict__ zbuf, float* __restrict__ wcb, float* __restrict__ b1tb)
{
    const int tid = threadIdx.x;
    if (blockIdx.x == 2048) {
        const int n = tid;               // 0..127
        float wc[32];
#pragma unroll
        for (int c = 0; c < 32; ++c) wc[c] = 0.0f;
        float bc = 0.0f, bb = 0.0f;
        const float* w1a = w1 + n * 256;
        const float* w1b = w1a + 128;
        for (int k = 0; k < 128; ++k) {
            const float a = w1b[k];
            bc += a * xb[k];
            bb += w1a[k] * lnb[k];
            const float* xr = xw + k * 32;
#pragma unroll
            for (int c = 0; c < 32; ++c) wc[c] = fmaf(a, xr[c], wc[c]);
        }
#pragma unroll
        for (int c = 0; c < 32; ++c) wcb[n * 32 + c] = wc[c];
        b1tb[n] = b1[n] + bc + bb;
        return;
    }
    __shared__ float p[32];
    __shared__ float x0[128];
    const int b = blockIdx.x;
    if (tid < 32) p[tid] = past[(long)b * 16384 + tid];
    __syncthreads();
    float s = xb[tid];
#pragma unroll
    for (int c = 0; c < 32; ++c) s += p[c] * xw[tid * 32 + c];
    x0[tid] = s;
    __syncthreads();
    float z = zb[tid];
    for (int k = 0; k < 128; ++k) z += x0[k] * zw[tid * 128 + k];
    zbuf[(long)b * 128 + tid] = z;
}

// ---------------------------------------------------------------------------
// ODE kernel v10: WAVE-AUTONOMOUS. grid 128 blocks x 64 threads (1 wave).
// Each wave owns 16 batch rows and computes ALL 128 cols of every layer:
// layer-to-layer exchange is a same-wave LDS round-trip (C-frag -> A-frag via
// the v8-proven PERM pair layout). ZERO s_barrier in the 128-eval loop; the
// compiler's automatic lgkmcnt insertion orders the same-wave LDS traffic.
//  - w1a (gamma-folded) + Wc + w2 as pre-arranged B-fragments in LDS
//    (wfrag[idx][lane], conflict-free 16B/lane reads); w3 in registers.
//  - LN beta folded into b1t (from z0wc); stats via fdot2 + 2 shfl.
//  - bx streamed from global per eval (prefetched ~1 phase ahead).
// PERM: stored elem j of a 32-block <-> true k = ks*32 + lhi*4 + PERM[j].
// ---------------------------------------------------------------------------
__global__ __launch_bounds__(64, 1) void ode_kernel(
    const float* __restrict__ past,
    const float* __restrict__ ln_g,
    const float* __restrict__ w1,
    const float* __restrict__ wcb, const float* __restrict__ b1tb,
    const float* __restrict__ w2, const float* __restrict__ b2,
    const float* __restrict__ w3, const float* __restrict__ b3,
    float* __restrict__ zbuf)
{
    __shared__ h8f16 wfrag[72][64];          // 72 KB: w1a 0..31, wc 32..39, w2 40..71
    __shared__ _Float16 vS[16][136];         // activations (PERM pair layout)
    __shared__ _Float16 h1S[16][136];
    __shared__ _Float16 h2S[16][136];

    const int lane = threadIdx.x;
    const int lrow = lane & 15;
    const int lhi  = lane >> 4;
    const int koff = lhi * 8;
    const int b0   = blockIdx.x * 16;
    const int PERM[8] = {0, 16, 1, 17, 2, 18, 3, 19};

    // ---- preload weights: w1a/wc/w2 -> LDS frags, w3 -> registers ----
    h8f16 w3f[8][4];
    float b1r[8], b2r[8], b3r[8];
#pragma unroll
    for (int t = 0; t < 8; ++t) {
        const int n = t * 16 + lrow;
#pragma unroll
        for (int ks = 0; ks < 4; ++ks) {
            h8f16 v1, v2, v3;
#pragma unroll
            for (int j = 0; j < 8; ++j) {
                const int k = ks * 32 + lhi * 4 + PERM[j];
                v1[j] = (_Float16)(w1[n * 256 + k] * ln_g[k]);
                v2[j] = (_Float16)w2[n * 128 + k];
                v3[j] = (_Float16)w3[n * 128 + k];
            }
            wfrag[t * 4 + ks][lane] = v1;
            wfrag[40 + t * 4 + ks][lane] = v2;
            w3f[t][ks] = v3;
        }
        {
            h8f16 v;
#pragma unroll
            for (int j = 0; j < 8; ++j) v[j] = (_Float16)wcb[n * 32 + koff + j];
            wfrag[32 + t][lane] = v;
        }
        b1r[t] = b1tb[n]; b2r[t] = b2[n]; b3r[t] = b3[n];
    }

    // ---- state: z in C-frag layout (rows 4*lhi+j, col 16t+lrow) ----
    float zc[8][4], krk[8][4];
#pragma unroll
    for (int t = 0; t < 8; ++t)
#pragma unroll
        for (int j = 0; j < 4; ++j)
            zc[t][j] = zbuf[(long)(b0 + 4 * lhi + j) * 128 + t * 16 + lrow];
#pragma unroll
    for (int t2 = 0; t2 < 4; ++t2)
#pragma unroll
        for (int j = 0; j < 4; ++j)
            *(h2f16*)&vS[4 * lhi + j][32 * t2 + 2 * lrow] =
                (h2f16){(_Float16)zc[2 * t2][j], (_Float16)zc[2 * t2 + 1][j]};

    const float DT = 1.0f / 32.0f;
    const h2f16 one2 = {(_Float16)1.0f, (_Float16)1.0f};

    // ---- bx streaming (prefetched ~1 phase ahead; no barriers to drain it) ----
    f32x4 s0a, s0b, s1a, s1b;
    auto stage = [&](int e) {
        const float pos = (float)e * 7.984375f;   // e*(511/64), exact
        const int i0 = (int)pos;
        const int i1 = (i0 < 511) ? i0 + 1 : 511;
        const float* base = past + (long)(b0 + lrow) * 16384;
        const float* p0 = base + i0 * 32 + koff;
        const float* p1 = base + i1 * 32 + koff;
        s0a = *(const f32x4*)p0; s0b = *(const f32x4*)(p0 + 4);
        s1a = *(const f32x4*)p1; s1b = *(const f32x4*)(p1 + 4);
    };
    auto blend = [&](int e) -> h8f16 {
        const float pos = (float)e * 7.984375f;
        const float w = pos - floorf(pos);
        h8f16 r;
#pragma unroll
        for (int j = 0; j < 4; ++j) {
            r[j]     = (_Float16)(s0a[j] + w * (s1a[j] - s0a[j]));
            r[4 + j] = (_Float16)(s0b[j] + w * (s1b[j] - s0b[j]));
        }
        return r;
    };

    // ---- one odef eval; k output left in acc (C-frag layout) ----
    f32x4 acc[8];
    auto eval = [&](h8f16 bxc) {
        h8f16 xf[4];
#pragma unroll
        for (int ks = 0; ks < 4; ++ks)
            xf[ks] = *(const h8f16*)&vS[lrow][ks * 32 + koff];
        // LN stats (order-invariant under PERM)
        float s0 = 0.f, s1 = 0.f, q0 = 0.f, q1 = 0.f;
#pragma unroll
        for (int ks = 0; ks < 4; ++ks) {
#pragma unroll
            for (int p = 0; p < 4; ++p) {
                const h2f16 x2 = {xf[ks][2 * p], xf[ks][2 * p + 1]};
                if (p & 1) {
                    s1 = __builtin_amdgcn_fdot2(x2, one2, s1, false);
                    q1 = __builtin_amdgcn_fdot2(x2, x2, q1, false);
                } else {
                    s0 = __builtin_amdgcn_fdot2(x2, one2, s0, false);
                    q0 = __builtin_amdgcn_fdot2(x2, x2, q0, false);
                }
            }
        }
        float s = s0 + s1, q = q0 + q1;
        s += __shfl_xor(s, 16); q += __shfl_xor(q, 16);
        s += __shfl_xor(s, 32); q += __shfl_xor(q, 32);
        const float mu  = s * (1.0f / 128.0f);
        const float var = q * (1.0f / 128.0f) - mu * mu;
        const float inv = 1.0f / sqrtf(var + 1e-5f);
        const _Float16 ih = (_Float16)inv;
        const _Float16 mh = (_Float16)(-mu * inv);
        h8f16 ip, mp;
#pragma unroll
        for (int j = 0; j < 8; ++j) { ip[j] = ih; mp[j] = mh; }
        h8f16 az[4];
#pragma unroll
        for (int ks = 0; ks < 4; ++ks) az[ks] = xf[ks] * ip + mp;

        // layer 1: 40 MFMA (w1a from LDS frags + Wc)
#pragma unroll
        for (int t = 0; t < 8; ++t) acc[t] = (f32x4){0, 0, 0, 0};
#pragma unroll
        for (int ks = 0; ks < 4; ++ks)
#pragma unroll
            for (int t = 0; t < 8; ++t)
                acc[t] = MFMA16(az[ks], wfrag[t * 4 + ks][lane], acc[t]);
#pragma unroll
        for (int t = 0; t < 8; ++t)
            acc[t] = MFMA16(bxc, wfrag[32 + t][lane], acc[t]);
#pragma unroll
        for (int t2 = 0; t2 < 4; ++t2)
#pragma unroll
            for (int j = 0; j < 4; ++j) {
                const _Float16 o0 = (_Float16)silu_f(acc[2 * t2][j] + b1r[2 * t2]);
                const _Float16 o1 = (_Float16)silu_f(acc[2 * t2 + 1][j] + b1r[2 * t2 + 1]);
                *(h2f16*)&h1S[4 * lhi + j][32 * t2 + 2 * lrow] = (h2f16){o0, o1};
            }

        // layer 2: 32 MFMA (w2 from LDS frags)
        h8f16 a1[4];
#pragma unroll
        for (int ks = 0; ks < 4; ++ks)
            a1[ks] = *(const h8f16*)&h1S[lrow][ks * 32 + koff];
#pragma unroll
        for (int t = 0; t < 8; ++t) acc[t] = (f32x4){0, 0, 0, 0};
#pragma unroll
        for (int ks = 0; ks < 4; ++ks)
#pragma unroll
            for (int t = 0; t < 8; ++t)
                acc[t] = MFMA16(a1[ks], wfrag[40 + t * 4 + ks][lane], acc[t]);
#pragma unroll
        for (int t2 = 0; t2 < 4; ++t2)
#pragma unroll
            for (int j = 0; j < 4; ++j) {
                const _Float16 o0 = (_Float16)silu_f(acc[2 * t2][j] + b2r[2 * t2]);
                const _Float16 o1 = (_Float16)silu_f(acc[2 * t2 + 1][j] + b2r[2 * t2 + 1]);
                *(h2f16*)&h2S[4 * lhi + j][32 * t2 + 2 * lrow] = (h2f16){o0, o1};
            }

        // layer 3: 32 MFMA (w3 from registers); k stays in acc
        h8f16 a2[4];
#pragma unroll
        for (int ks = 0; ks < 4; ++ks)
            a2[ks] = *(const h8f16*)&h2S[lrow][ks * 32 + koff];
#pragma unroll
        for (int t = 0; t < 8; ++t) acc[t] = (f32x4){0, 0, 0, 0};
#pragma unroll
        for (int ks = 0; ks < 4; ++ks)
#pragma unroll
            for (int t = 0; t < 8; ++t)
                acc[t] = MFMA16(a2[ks], w3f[t][ks], acc[t]);
    };

    auto writeV = [&](int t2, int j, float v0, float v1) {
        *(h2f16*)&vS[4 * lhi + j][32 * t2 + 2 * lrow] =
            (h2f16){(_Float16)v0, (_Float16)v1};
    };

    stage(0);
    h8f16 bxc = blend(0);

#pragma unroll 1
    for (int st = 0; st < 32; ++st) {
        const int e1 = 2 * st + 1, e2 = 2 * st + 2;
        // ---- sub0: k1 ----
        eval(bxc);
        stage(e1);
#pragma unroll
        for (int t2 = 0; t2 < 4; ++t2)
#pragma unroll
            for (int j = 0; j < 4; ++j) {
                const float k0 = acc[2 * t2][j] + b3r[2 * t2];
                const float k1 = acc[2 * t2 + 1][j] + b3r[2 * t2 + 1];
                krk[2 * t2][j] = k0; krk[2 * t2 + 1][j] = k1;
                writeV(t2, j, zc[2 * t2][j] + 0.5f * DT * k0,
                              zc[2 * t2 + 1][j] + 0.5f * DT * k1);
            }
        // ---- sub1: k2 ----
        bxc = blend(e1);
        eval(bxc);
#pragma unroll
        for (int t2 = 0; t2 < 4; ++t2)
#pragma unroll
            for (int j = 0; j < 4; ++j) {
                const float k0 = acc[2 * t2][j] + b3r[2 * t2];
                const float k1 = acc[2 * t2 + 1][j] + b3r[2 * t2 + 1];
                krk[2 * t2][j] += 2.0f * k0; krk[2 * t2 + 1][j] += 2.0f * k1;
                writeV(t2, j, zc[2 * t2][j] + 0.5f * DT * k0,
                              zc[2 * t2 + 1][j] + 0.5f * DT * k1);
            }
        // ---- sub2: k3 ----
        eval(bxc);
        stage(e2);
#pragma unroll
        for (int t2 = 0; t2 < 4; ++t2)
#pragma unroll
            for (int j = 0; j < 4; ++j) {
                const float k0 = acc[2 * t2][j] + b3r[2 * t2];
                const float k1 = acc[2 * t2 + 1][j] + b3r[2 * t2 + 1];
                krk[2 * t2][j] += 2.0f * k0; krk[2 * t2 + 1][j] += 2.0f * k1;
                writeV(t2, j, zc[2 * t2][j] + DT * k0,
                              zc[2 * t2 + 1][j] + DT * k1);
            }
        // ---- sub3: k4 + z update ----
        bxc = blend(e2);
        eval(bxc);
#pragma unroll
        for (int t2 = 0; t2 < 4; ++t2)
#pragma unroll
            for (int j = 0; j < 4; ++j) {
                const float k0 = acc[2 * t2][j] + b3r[2 * t2];
                const float k1 = acc[2 * t2 + 1][j] + b3r[2 * t2 + 1];
                zc[2 * t2][j]     += (DT / 6.0f) * (krk[2 * t2][j] + k0);
                zc[2 * t2 + 1][j] += (DT / 6.0f) * (krk[2 * t2 + 1][j] + k1);
                writeV(t2, j, zc[2 * t2][j], zc[2 * t2 + 1][j]);
            }
    }

#pragma unroll
    for (int t = 0; t < 8; ++t)
#pragma unroll
        for (int j = 0; j < 4; ++j)
            zbuf[(long)(b0 + 4 * lhi + j) * 128 + t * 16 + lrow] = zc[t][j];
}

// ---------------------------------------------------------------------------
// gemm1x: h1pre = x_t @ fw1[:, :3072].T   (f32 out, no bias)
// M=2048 N=256 K=3072, tile 64x64, grid (32,4) x 256 threads.
// ---------------------------------------------------------------------------
__global__ __launch_bounds__(256) void gemm1x_kernel(
    const float* __restrict__ x_t, const float* __restrict__ fw1,
    float* __restrict__ h1pre)
{
    __shared__ _Float16 aS[64][40];
    __shared__ _Float16 wS[64][40];
    const int mb = blockIdx.x * 64, nb = blockIdx.y * 64;
    const int tid = threadIdx.x, lane = tid & 63, wq = tid >> 6;
    const int lrow = lane & 15, lhi = lane >> 4;
    f32x4 acc[4];
#pragma unroll
    for (int nt = 0; nt < 4; ++nt) acc[nt] = (f32x4){0, 0, 0, 0};

    const int sr = tid >> 2;
    const int sk = (tid & 3) * 8;

    for (int k0 = 0; k0 < 3072; k0 += 32) {
        {
            const float* s = x_t + (long)(mb + sr) * 3072 + k0 + sk;
            const f32x4 u0 = *(const f32x4*)s;
            const f32x4 u1 = *(const f32x4*)(s + 4);
            h8f16 v;
#pragma unroll
            for (int j = 0; j < 4; ++j) { v[j] = (_Float16)u0[j]; v[4 + j] = (_Float16)u1[j]; }
            *(h8f16*)&aS[sr][sk] = v;
        }
        {
            const float* s = fw1 + (long)(nb + sr) * 3328 + k0 + sk;
            const f32x4 u0 = *(const f32x4*)s;
            const f32x4 u1 = *(const f32x4*)(s + 4);
            h8f16 v;
#pragma unroll
            for (int j = 0; j < 4; ++j) { v[j] = (_Float16)u0[j]; v[4 + j] = (_Float16)u1[j]; }
            *(h8f16*)&wS[sr][sk] = v;
        }
        __syncthreads();
        const h8f16 a = *(const h8f16*)&aS[wq * 16 + lrow][lhi * 8];
#pragma unroll
        for (int nt = 0; nt < 4; ++nt) {
            const h8f16 bfr = *(const h8f16*)&wS[nt * 16 + lrow][lhi * 8];
            acc[nt] = MFMA16(a, bfr, acc[nt]);
        }
        __syncthreads();
    }

#pragma unroll
    for (int nt = 0; nt < 4; ++nt) {
        const int cc = nb + nt * 16 + lrow;
#pragma unroll
        for (int j = 0; j < 4; ++j) {
            const int rr = mb + wq * 16 + lhi * 4 + j;
            h1pre[(long)rr * 256 + cc] = acc[nt][j];
        }
    }
}

// ---------------------------------------------------------------------------
// temb: tbuf[b][0:128] = [sin|cos] time embedding (f16). grid 16 x 256.
// ---------------------------------------------------------------------------
__global__ __launch_bounds__(256) void temb_kernel(
    const int* __restrict__ tvals, _Float16* __restrict__ tbuf)
{
    const int tid = threadIdx.x;
#pragma unroll 1
    for (int c = 0; c < 8; ++c) {
        const int chunk = blockIdx.x * 256 + tid + c * 4096;
        const int b  = chunk >> 4;
        const int j0 = (chunk & 15) * 8;
        const float tv = (float)tvals[b];
        h8f16 v;
#pragma unroll
        for (int j = 0; j < 8; ++j) {
            const int jj  = j0 + j;
            const int idx = (jj < 64) ? jj : jj - 64;
            const float fr = expf(-9.210340371976184f * (float)idx * (1.0f / 63.0f));
            const float a  = tv * fr;
            v[j] = (_Float16)((jj < 64) ? sinf(a) : cosf(a));
        }
        *(h8f16*)&tbuf[(long)b * 128 + j0] = v;
    }
}

// ---------------------------------------------------------------------------
// gemm1c: h1 = silu(h1pre + [cond(f32)|temb(f16)] @ fw1[:,3072:].T + fb1)
// ---------------------------------------------------------------------------
__global__ __launch_bounds__(256) void gemm1c_kernel(
    const float* __restrict__ cond, const _Float16* __restrict__ tbuf,
    const float* __restrict__ fw1, const float* __restrict__ fb1,
    const float* __restrict__ h1pre, _Float16* __restrict__ h1)
{
    __shared__ _Float16 aS[64][40];
    __shared__ _Float16 wS[64][40];
    const int mb = blockIdx.x * 64, nb = blockIdx.y * 64;
    const int tid = threadIdx.x, lane = tid & 63, wq = tid >> 6;
    const int lrow = lane & 15, lhi = lane >> 4;
    f32x4 acc[4];
#pragma unroll
    for (int nt = 0; nt < 4; ++nt) acc[nt] = (f32x4){0, 0, 0, 0};

    const int sr = tid >> 2;
    const int sk = (tid & 3) * 8;

    for (int k0 = 0; k0 < 256; k0 += 32) {
        if (k0 < 128) {
            const float* s = cond + (long)(mb + sr) * 128 + k0 + sk;
            const f32x4 u0 = *(const f32x4*)s;
            const f32x4 u1 = *(const f32x4*)(s + 4);
            h8f16 v;
#pragma unroll
            for (int j = 0; j < 4; ++j) { v[j] = (_Float16)u0[j]; v[4 + j] = (_Float16)u1[j]; }
            *(h8f16*)&aS[sr][sk] = v;
        } else {
            *(h8f16*)&aS[sr][sk] =
                *(const h8f16*)&tbuf[(long)(mb + sr) * 128 + (k0 - 128) + sk];
        }
        {
            const float* s = fw1 + (long)(nb + sr) * 3328 + 3072 + k0 + sk;
            h8f16 v;
#pragma unroll
            for (int j = 0; j < 8; ++j) v[j] = (_Float16)s[j];
            *(h8f16*)&wS[sr][sk] = v;
        }
        __syncthreads();
        const h8f16 a = *(const h8f16*)&aS[wq * 16 + lrow][lhi * 8];
#pragma unroll
        for (int nt = 0; nt < 4; ++nt) {
            const h8f16 bfr = *(const h8f16*)&wS[nt * 16 + lrow][lhi * 8];
            acc[nt] = MFMA16(a, bfr, acc[nt]);
        }
        __syncthreads();
    }

#pragma unroll
    for (int nt = 0; nt < 4; ++nt) {
        const int cc = nb + nt * 16 + lrow;
        const float bv = fb1[cc];
#pragma unroll
        for (int j = 0; j < 4; ++j) {
            const int rr = mb + wq * 16 + lhi * 4 + j;
            const float v = acc[nt][j] + h1pre[(long)rr * 256 + cc] + bv;
            h1[(long)rr * 256 + cc] = (_Float16)silu_f(v);
        }
    }
}

// ---------------------------------------------------------------------------
// Generic f16-MFMA GEMM: out(M,N) = [silu](A(M,K) @ W(N,K).T + bias)
// ---------------------------------------------------------------------------
template <bool SILU, bool OUT_F16>
__global__ __launch_bounds__(256) void gemm_f16(
    const _Float16* __restrict__ A, const float* __restrict__ W,
    const float* __restrict__ bias, void* __restrict__ out,
    int M, int N, int K)
{
    __shared__ _Float16 aS[64][40];
    __shared__ _Float16 wS[64][40];
    const int mb = blockIdx.x * 64, nb = blockIdx.y * 64;
    const int tid = threadIdx.x, lane = tid & 63, wq = tid >> 6;
    const int lrow = lane & 15, lhi = lane >> 4;
    f32x4 acc[4];
#pragma unroll
    for (int nt = 0; nt < 4; ++nt) acc[nt] = (f32x4){0, 0, 0, 0};

    const int sr = tid >> 2;
    const int sk = (tid & 3) * 8;

    for (int k0 = 0; k0 < K; k0 += 32) {
        {
            h8f16 v = *(const h8f16*)&A[(long)(mb + sr) * K + k0 + sk];
            *(h8f16*)&aS[sr][sk] = v;
        }
        {
            const float* s = &W[(long)(nb + sr) * K + k0 + sk];
            h8f16 v;
#pragma unroll
            for (int j = 0; j < 8; ++j) v[j] = (_Float16)s[j];
            *(h8f16*)&wS[sr][sk] = v;
        }
        __syncthreads();
        h8f16 a = *(const h8f16*)&aS[wq * 16 + lrow][lhi * 8];
#pragma unroll
        for (int nt = 0; nt < 4; ++nt) {
            h8f16 bfr = *(const h8f16*)&wS[nt * 16 + lrow][lhi * 8];
            acc[nt] = MFMA16(a, bfr, acc[nt]);
        }
        __syncthreads();
    }

#pragma unroll
    for (int nt = 0; nt < 4; ++nt) {
        const int cc = nb + nt * 16 + lrow;
        const float bv = bias[cc];
#pragma unroll
        for (int j = 0; j < 4; ++j) {
            const int rr = mb + wq * 16 + lhi * 4 + j;
            float v = acc[nt][j] + bv;
            if (SILU) v = silu_f(v);
            if (OUT_F16) ((_Float16*)out)[(long)rr * N + cc] = (_Float16)v;
            else         ((float*)out)[(long)rr * N + cc] = v;
        }
    }
}

// ---------------------------------------------------------------------------
extern "C" void kernel_launch(void* const* d_in, const int* in_sizes, int n_in,
                              void* d_out, int out_size, void* d_ws, size_t ws_size,
                              hipStream_t stream)
{
    const float* x_t     = (const float*)d_in[0];
    const float* past    = (const float*)d_in[1];
    const int*   tvals   = (const int*)d_in[2];
    const float* xproj_w = (const float*)d_in[3];
    const float* xproj_b = (const float*)d_in[4];
    const float* z0_w    = (const float*)d_in[5];
    const float* z0_b    = (const float*)d_in[6];
    const float* ln_g    = (const float*)d_in[7];
    const float* ln_b    = (const float*)d_in[8];
    const float* w1      = (const float*)d_in[9];
    const float* b1      = (const float*)d_in[10];
    const float* w2      = (const float*)d_in[11];
    const float* b2      = (const float*)d_in[12];
    const float* w3      = (const float*)d_in[13];
    const float* b3      = (const float*)d_in[14];
    const float* fw1     = (const float*)d_in[15];
    const float* fb1     = (const float*)d_in[16];
    const float* fw2     = (const float*)d_in[17];
    const float* fb2     = (const float*)d_in[18];
    const float* fw3     = (const float*)d_in[19];
    const float* fb3     = (const float*)d_in[20];

    char* ws = (char*)d_ws;
    float*     zbuf  = (float*)ws;                        // 1 MB   (B*128 f32)
    _Float16*  tbuf  = (_Float16*)(ws + (1 << 20));       // 0.5 MB
    float*     h1pre = (float*)(ws + 2 * (1 << 20));      // 2 MB   (B*256 f32)
    _Float16*  h1    = (_Float16*)(ws + 4 * (1 << 20));   // 1 MB
    _Float16*  h2    = (_Float16*)(ws + 5 * (1 << 20));   // 1 MB
    float*     wcb   = (float*)(ws + 6 * (1 << 20));      // 16 KB  (128x32 f32)
    float*     b1tb  = (float*)(ws + 6 * (1 << 20) + (1 << 16));  // 512 B

    z0wc_kernel<<<2049, 128, 0, stream>>>(past, xproj_w, xproj_b, z0_w, z0_b,
                                          w1, ln_b, b1, zbuf, wcb, b1tb);

    ode_kernel<<<128, 64, 0, stream>>>(past, ln_g, w1, wcb, b1tb,
                                       w2, b2, w3, b3, zbuf);

    gemm1x_kernel<<<dim3(32, 4), 256, 0, stream>>>(x_t, fw1, h1pre);
    temb_kernel<<<16, 256, 0, stream>>>(tvals, tbuf);

    gemm1c_kernel<<<dim3(32, 4), 256, 0, stream>>>(zbuf, tbuf, fw1, fb1, h1pre, h1);

    gemm_f16<true,  true ><<<dim3(32, 4),  256, 0, stream>>>(h1, fw2, fb2, h2, 2048, 256, 256);
    gemm_f16<false, false><<<dim3(32, 48), 256, 0, stream>>>(h2, fw3, fb3, d_out, 2048, 3072, 256);
}

// Round 12
// 361.993 us; speedup vs baseline: 2.0779x; 2.0779x over previous
//
#include <hip/hip_runtime.h>
#include <math.h>

typedef _Float16 h8f16 __attribute__((ext_vector_type(8)));
typedef _Float16 h2f16 __attribute__((ext_vector_type(2)));
typedef float f32x4 __attribute__((ext_vector_type(4)));

#define MFMA16(a, b, c) __builtin_amdgcn_mfma_f32_16x16x32_f16((a), (b), (c), 0, 0, 0)

__device__ __forceinline__ float silu_f(float v) {
    return v * __builtin_amdgcn_rcpf(1.0f + __expf(-v));
}

// Bare barrier: writer-side LDS completion + s_barrier, NO vmcnt drain.
__device__ __forceinline__ void bar_lds() {
    asm volatile("s_waitcnt lgkmcnt(0)" ::: "memory");
    __builtin_amdgcn_s_barrier();
    __builtin_amdgcn_sched_barrier(0);
}

// ---------------------------------------------------------------------------
// ODE mega-kernel v6 (proven 258 us): 32 RK4 steps, bare barriers, fdot2 LN
// stats, gamma/beta folded, bx streamed from global (never vmcnt-drained).
// grid: 128 blocks (16 batch rows) x 512 threads (8 waves; wave w owns output
// cols [16w,16w+16)). z0 computed in the prologue (f32 exact).
// ---------------------------------------------------------------------------
__global__ __launch_bounds__(512, 1) void ode_kernel(
    const float* __restrict__ past,
    const float* __restrict__ xproj_w, const float* __restrict__ xproj_b,
    const float* __restrict__ z0_w, const float* __restrict__ z0_b,
    const float* __restrict__ ln_g, const float* __restrict__ ln_b,
    const float* __restrict__ w1, const float* __restrict__ b1,
    const float* __restrict__ w2, const float* __restrict__ b2,
    const float* __restrict__ w3, const float* __restrict__ b3,
    float* __restrict__ zbuf)
{
    __shared__ _Float16 hbuf[16][136];   // LN input v
    __shared__ _Float16 h1S[16][136];
    __shared__ _Float16 h2S[16][136];
    __shared__ float    pS[16][33];      // prologue stages
    __shared__ float    x0S[16][128];
    __shared__ float    zS0[16][129];

    const int tid  = threadIdx.x;
    const int wid  = tid >> 6;
    const int lane = tid & 63;
    const int lrow = lane & 15;
    const int lhi  = lane >> 4;
    const int b0   = blockIdx.x * 16;
    const int nc   = wid * 16 + lrow;    // this lane's output col (all layers)
    const int koff = lhi * 8;

    // ---- weights into register B-fragments; gamma folded into W1a ----
    h8f16 w1f[4], wcf, w2f[4], w3f[4];
    float b1t, b2r, b3r;
    {
#pragma unroll
        for (int ks = 0; ks < 4; ++ks) {
            h8f16 v1, v2, v3;
#pragma unroll
            for (int j = 0; j < 8; ++j) {
                const int k = ks * 32 + koff + j;
                v1[j] = (_Float16)(w1[nc * 256 + k] * ln_g[k]);
                v2[j] = (_Float16)w2[nc * 128 + k];
                v3[j] = (_Float16)w3[nc * 128 + k];
            }
            w1f[ks] = v1; w2f[ks] = v2; w3f[ks] = v3;
        }
        // Wc = W1b @ xproj_w ; bc = W1b @ xproj_b ; bb = W1a @ ln_b
        float wc[8] = {0, 0, 0, 0, 0, 0, 0, 0};
        float bc = 0.0f, bb = 0.0f;
        const float* w1a = w1 + nc * 256;
        const float* w1b = w1a + 128;
#pragma unroll 4
        for (int k = 0; k < 128; ++k) {
            const float a = w1b[k];
            bc += a * xproj_b[k];
            bb += w1a[k] * ln_b[k];
            const float* xr = xproj_w + k * 32 + koff;
#pragma unroll
            for (int j = 0; j < 8; ++j) wc[j] += a * xr[j];
        }
        h8f16 v;
#pragma unroll
        for (int j = 0; j < 8; ++j) v[j] = (_Float16)wc[j];
        wcf = v;
        b1t = b1[nc] + bc + bb;
        b2r = b2[nc]; b3r = b3[nc];
    }

    // ---- prologue: z0 = (past[:,0,:] @ xw.T + xb) @ z0w.T + z0b (f32) ----
    pS[tid >> 5][tid & 31] = past[(long)(b0 + (tid >> 5)) * 16384 + (tid & 31)];
    __syncthreads();
    {
        const int r  = tid >> 5;
        const int c0 = (tid & 31) * 4;
#pragma unroll
        for (int cc = 0; cc < 4; ++cc) {
            const int kc = c0 + cc;
            float s = xproj_b[kc];
            const float* xr = xproj_w + kc * 32;
#pragma unroll
            for (int c = 0; c < 32; ++c) s += pS[r][c] * xr[c];
            x0S[r][kc] = s;
        }
    }
    __syncthreads();
    {
        const int nn = tid & 127;
        const int r0 = (tid >> 7) * 4;
        for (int p = 0; p < 4; ++p) {
            const int r = r0 + p;
            float s = z0_b[nn];
            const float* zr = z0_w + nn * 128;
            for (int k = 0; k < 128; ++k) s += x0S[r][k] * zr[k];
            zS0[r][nn] = s;
        }
    }
    __syncthreads();

    // ---- z cached per-lane in C-frag layout (rows 4*lhi+j, col nc) ----
    float zc[4], krk[4];
#pragma unroll
    for (int j = 0; j < 4; ++j) {
        zc[j] = zS0[4 * lhi + j][nc];
        hbuf[4 * lhi + j][nc] = (_Float16)zc[j];
    }

    const float DT = 1.0f / 32.0f;

    // ---- bx streaming (global loads; never drained in-loop) ----
    f32x4 s0a, s0b, s1a, s1b;
    auto stage = [&](int e) {
        const float pos = (float)e * 7.984375f;   // e*(511/64), exact
        const int i0 = (int)pos;
        const int i1 = (i0 < 511) ? i0 + 1 : 511;
        const float* base = past + (long)(b0 + lrow) * 16384;
        const float* p0 = base + i0 * 32 + koff;
        const float* p1 = base + i1 * 32 + koff;
        s0a = *(const f32x4*)p0; s0b = *(const f32x4*)(p0 + 4);
        s1a = *(const f32x4*)p1; s1b = *(const f32x4*)(p1 + 4);
    };
    auto blend = [&](int e) -> h8f16 {
        const float pos = (float)e * 7.984375f;
        const float w = pos - floorf(pos);
        h8f16 r;
#pragma unroll
        for (int j = 0; j < 4; ++j) {
            r[j]     = (_Float16)(s0a[j] + w * (s1a[j] - s0a[j]));
            r[4 + j] = (_Float16)(s0b[j] + w * (s1b[j] - s0b[j]));
        }
        return r;
    };

    const h2f16 one2 = {(_Float16)1.0f, (_Float16)1.0f};

    auto phaseA = [&](h8f16 bxc) {
        h8f16 xf[4];
#pragma unroll
        for (int ks = 0; ks < 4; ++ks)
            xf[ks] = *(const h8f16*)&hbuf[lrow][ks * 32 + koff];
        // LN stats via v_dot2_f32_f16 (2 independent accumulator chains each)
        float s0 = 0.f, s1 = 0.f, q0 = 0.f, q1 = 0.f;
#pragma unroll
        for (int ks = 0; ks < 4; ++ks) {
#pragma unroll
            for (int p = 0; p < 4; ++p) {
                const h2f16 x2 = {xf[ks][2 * p], xf[ks][2 * p + 1]};
                if (p & 1) {
                    s1 = __builtin_amdgcn_fdot2(x2, one2, s1, false);
                    q1 = __builtin_amdgcn_fdot2(x2, x2, q1, false);
                } else {
                    s0 = __builtin_amdgcn_fdot2(x2, one2, s0, false);
                    q0 = __builtin_amdgcn_fdot2(x2, x2, q0, false);
                }
            }
        }
        float s = s0 + s1, q = q0 + q1;
        s += __shfl_xor(s, 16); q += __shfl_xor(q, 16);
        s += __shfl_xor(s, 32); q += __shfl_xor(q, 32);
        const float mu  = s * (1.0f / 128.0f);
        const float var = q * (1.0f / 128.0f) - mu * mu;
        const float inv = 1.0f / sqrtf(var + 1e-5f);
        const _Float16 ih = (_Float16)inv;
        const _Float16 mh = (_Float16)(-mu * inv);
        h8f16 ip, mp;
#pragma unroll
        for (int j = 0; j < 8; ++j) { ip[j] = ih; mp[j] = mh; }
        f32x4 acc = {0, 0, 0, 0};
#pragma unroll
        for (int ks = 0; ks < 4; ++ks) {
            const h8f16 az = xf[ks] * ip + mp;   // packed f16 LN-apply (γ,β folded)
            acc = MFMA16(az, w1f[ks], acc);
        }
        acc = MFMA16(bxc, wcf, acc);
#pragma unroll
        for (int j = 0; j < 4; ++j)
            h1S[4 * lhi + j][nc] = (_Float16)silu_f(acc[j] + b1t);
    };
    auto phaseB = [&]() {
        f32x4 acc = {0, 0, 0, 0};
#pragma unroll
        for (int ks = 0; ks < 4; ++ks) {
            const h8f16 a = *(const h8f16*)&h1S[lrow][ks * 32 + koff];
            acc = MFMA16(a, w2f[ks], acc);
        }
#pragma unroll
        for (int j = 0; j < 4; ++j)
            h2S[4 * lhi + j][nc] = (_Float16)silu_f(acc[j] + b2r);
    };
    auto phaseC = [&]() -> f32x4 {
        f32x4 acc = {0, 0, 0, 0};
#pragma unroll
        for (int ks = 0; ks < 4; ++ks) {
            const h8f16 a = *(const h8f16*)&h2S[lrow][ks * 32 + koff];
            acc = MFMA16(a, w3f[ks], acc);
        }
#pragma unroll
        for (int j = 0; j < 4; ++j) acc[j] += b3r;
        return acc;
    };

    stage(0);
    h8f16 bxc = blend(0);
    __syncthreads();

#pragma unroll 1
    for (int st = 0; st < 32; ++st) {
        const int e1 = 2 * st + 1, e2 = 2 * st + 2;
        // ---- sub0: k1 ----
        phaseA(bxc);
        stage(e1);                                   // prefetch tile e1 (stays in flight)
        bar_lds();
        phaseB(); bar_lds();
        {
            const f32x4 k = phaseC();
#pragma unroll
            for (int j = 0; j < 4; ++j) {
                krk[j] = k[j];
                hbuf[4 * lhi + j][nc] = (_Float16)(zc[j] + 0.5f * DT * k[j]);
            }
        }
        bar_lds();
        // ---- sub1: k2 ----
        bxc = blend(e1);
        phaseA(bxc); bar_lds();
        phaseB(); bar_lds();
        {
            const f32x4 k = phaseC();
#pragma unroll
            for (int j = 0; j < 4; ++j) {
                krk[j] += 2.0f * k[j];
                hbuf[4 * lhi + j][nc] = (_Float16)(zc[j] + 0.5f * DT * k[j]);
            }
        }
        bar_lds();
        // ---- sub2: k3 ----
        phaseA(bxc);
        stage(e2);                                   // prefetch tile e2
        bar_lds();
        phaseB(); bar_lds();
        {
            const f32x4 k = phaseC();
#pragma unroll
            for (int j = 0; j < 4; ++j) {
                krk[j] += 2.0f * k[j];
                hbuf[4 * lhi + j][nc] = (_Float16)(zc[j] + DT * k[j]);
            }
        }
        bar_lds();
        // ---- sub3: k4 + z update ----
        bxc = blend(e2);
        phaseA(bxc); bar_lds();
        phaseB(); bar_lds();
        {
            const f32x4 k = phaseC();
#pragma unroll
            for (int j = 0; j < 4; ++j) {
                zc[j] += (DT / 6.0f) * (krk[j] + k[j]);
                hbuf[4 * lhi + j][nc] = (_Float16)zc[j];
            }
        }
        bar_lds();
    }

#pragma unroll
    for (int j = 0; j < 4; ++j)
        zbuf[(long)(b0 + 4 * lhi + j) * 128 + nc] = zc[j];
}

// ---------------------------------------------------------------------------
// temb: tbuf[b][0:128] = [sin|cos] time embedding (f16). grid 16 x 256.
// ---------------------------------------------------------------------------
__global__ __launch_bounds__(256) void temb_kernel(
    const int* __restrict__ tvals, _Float16* __restrict__ tbuf)
{
    const int tid = threadIdx.x;
#pragma unroll 1
    for (int c = 0; c < 8; ++c) {
        const int chunk = blockIdx.x * 256 + tid + c * 4096;
        const int b  = chunk >> 4;
        const int j0 = (chunk & 15) * 8;
        const float tv = (float)tvals[b];
        h8f16 v;
#pragma unroll
        for (int j = 0; j < 8; ++j) {
            const int jj  = j0 + j;
            const int idx = (jj < 64) ? jj : jj - 64;
            const float fr = expf(-9.210340371976184f * (float)idx * (1.0f / 63.0f));
            const float a  = tv * fr;
            v[j] = (_Float16)((jj < 64) ? sinf(a) : cosf(a));
        }
        *(h8f16*)&tbuf[(long)b * 128 + j0] = v;
    }
}

// ---------------------------------------------------------------------------
// gemm1d: h1 = silu([x_t | cond | temb] @ fw1.T + fb1), direct staging
// (no hcat buffer). M=2048 N=256 K=3328. A cols: 0-3071 x_t (f32->f16),
// 3072-3199 zbuf (f32->f16), 3200-3327 tbuf (f16). Values bitwise-identical
// to the hcat path. grid (32,4) x 256 threads, tile 64x64.
// ---------------------------------------------------------------------------
__global__ __launch_bounds__(256) void gemm1d_kernel(
    const float* __restrict__ x_t, const float* __restrict__ cond,
    const _Float16* __restrict__ tbuf,
    const float* __restrict__ fw1, const float* __restrict__ fb1,
    _Float16* __restrict__ h1)
{
    __shared__ _Float16 aS[64][40];
    __shared__ _Float16 wS[64][40];
    const int mb = blockIdx.x * 64, nb = blockIdx.y * 64;
    const int tid = threadIdx.x, lane = tid & 63, wq = tid >> 6;
    const int lrow = lane & 15, lhi = lane >> 4;
    f32x4 acc[4];
#pragma unroll
    for (int nt = 0; nt < 4; ++nt) acc[nt] = (f32x4){0, 0, 0, 0};

    const int sr = tid >> 2;
    const int sk = (tid & 3) * 8;

    for (int k0 = 0; k0 < 3328; k0 += 32) {
        if (k0 < 3072) {
            const float* s = x_t + (long)(mb + sr) * 3072 + k0 + sk;
            const f32x4 u0 = *(const f32x4*)s;
            const f32x4 u1 = *(const f32x4*)(s + 4);
            h8f16 v;
#pragma unroll
            for (int j = 0; j < 4; ++j) { v[j] = (_Float16)u0[j]; v[4 + j] = (_Float16)u1[j]; }
            *(h8f16*)&aS[sr][sk] = v;
        } else if (k0 < 3200) {
            const float* s = cond + (long)(mb + sr) * 128 + (k0 - 3072) + sk;
            const f32x4 u0 = *(const f32x4*)s;
            const f32x4 u1 = *(const f32x4*)(s + 4);
            h8f16 v;
#pragma unroll
            for (int j = 0; j < 4; ++j) { v[j] = (_Float16)u0[j]; v[4 + j] = (_Float16)u1[j]; }
            *(h8f16*)&aS[sr][sk] = v;
        } else {
            *(h8f16*)&aS[sr][sk] =
                *(const h8f16*)&tbuf[(long)(mb + sr) * 128 + (k0 - 3200) + sk];
        }
        {
            const float* s = fw1 + (long)(nb + sr) * 3328 + k0 + sk;
            h8f16 v;
#pragma unroll
            for (int j = 0; j < 8; ++j) v[j] = (_Float16)s[j];
            *(h8f16*)&wS[sr][sk] = v;
        }
        __syncthreads();
        const h8f16 a = *(const h8f16*)&aS[wq * 16 + lrow][lhi * 8];
#pragma unroll
        for (int nt = 0; nt < 4; ++nt) {
            const h8f16 bfr = *(const h8f16*)&wS[nt * 16 + lrow][lhi * 8];
            acc[nt] = MFMA16(a, bfr, acc[nt]);
        }
        __syncthreads();
    }

#pragma unroll
    for (int nt = 0; nt < 4; ++nt) {
        const int cc = nb + nt * 16 + lrow;
        const float bv = fb1[cc];
#pragma unroll
        for (int j = 0; j < 4; ++j) {
            const int rr = mb + wq * 16 + lhi * 4 + j;
            h1[(long)rr * 256 + cc] = (_Float16)silu_f(acc[nt][j] + bv);
        }
    }
}

// ---------------------------------------------------------------------------
// Generic f16-MFMA GEMM: out(M,N) = [silu](A(M,K) @ W(N,K).T + bias)
// ---------------------------------------------------------------------------
template <bool SILU, bool OUT_F16>
__global__ __launch_bounds__(256) void gemm_f16(
    const _Float16* __restrict__ A, const float* __restrict__ W,
    const float* __restrict__ bias, void* __restrict__ out,
    int M, int N, int K)
{
    __shared__ _Float16 aS[64][40];
    __shared__ _Float16 wS[64][40];
    const int mb = blockIdx.x * 64, nb = blockIdx.y * 64;
    const int tid = threadIdx.x, lane = tid & 63, wq = tid >> 6;
    const int lrow = lane & 15, lhi = lane >> 4;
    f32x4 acc[4];
#pragma unroll
    for (int nt = 0; nt < 4; ++nt) acc[nt] = (f32x4){0, 0, 0, 0};

    const int sr = tid >> 2;
    const int sk = (tid & 3) * 8;

    for (int k0 = 0; k0 < K; k0 += 32) {
        {
            h8f16 v = *(const h8f16*)&A[(long)(mb + sr) * K + k0 + sk];
            *(h8f16*)&aS[sr][sk] = v;
        }
        {
            const float* s = &W[(long)(nb + sr) * K + k0 + sk];
            h8f16 v;
#pragma unroll
            for (int j = 0; j < 8; ++j) v[j] = (_Float16)s[j];
            *(h8f16*)&wS[sr][sk] = v;
        }
        __syncthreads();
        h8f16 a = *(const h8f16*)&aS[wq * 16 + lrow][lhi * 8];
#pragma unroll
        for (int nt = 0; nt < 4; ++nt) {
            h8f16 bfr = *(const h8f16*)&wS[nt * 16 + lrow][lhi * 8];
            acc[nt] = MFMA16(a, bfr, acc[nt]);
        }
        __syncthreads();
    }

#pragma unroll
    for (int nt = 0; nt < 4; ++nt) {
        const int cc = nb + nt * 16 + lrow;
        const float bv = bias[cc];
#pragma unroll
        for (int j = 0; j < 4; ++j) {
            const int rr = mb + wq * 16 + lhi * 4 + j;
            float v = acc[nt][j] + bv;
            if (SILU) v = silu_f(v);
            if (OUT_F16) ((_Float16*)out)[(long)rr * N + cc] = (_Float16)v;
            else         ((float*)out)[(long)rr * N + cc] = v;
        }
    }
}

// ---------------------------------------------------------------------------
extern "C" void kernel_launch(void* const* d_in, const int* in_sizes, int n_in,
                              void* d_out, int out_size, void* d_ws, size_t ws_size,
                              hipStream_t stream)
{
    const float* x_t     = (const float*)d_in[0];
    const float* past    = (const float*)d_in[1];
    const int*   tvals   = (const int*)d_in[2];
    const float* xproj_w = (const float*)d_in[3];
    const float* xproj_b = (const float*)d_in[4];
    const float* z0_w    = (const float*)d_in[5];
    const float* z0_b    = (const float*)d_in[6];
    const float* ln_g    = (const float*)d_in[7];
    const float* ln_b    = (const float*)d_in[8];
    const float* w1      = (const float*)d_in[9];
    const float* b1      = (const float*)d_in[10];
    const float* w2      = (const float*)d_in[11];
    const float* b2      = (const float*)d_in[12];
    const float* w3      = (const float*)d_in[13];
    const float* b3      = (const float*)d_in[14];
    const float* fw1     = (const float*)d_in[15];
    const float* fb1     = (const float*)d_in[16];
    const float* fw2     = (const float*)d_in[17];
    const float* fb2     = (const float*)d_in[18];
    const float* fw3     = (const float*)d_in[19];
    const float* fb3     = (const float*)d_in[20];

    char* ws = (char*)d_ws;
    float*     zbuf = (float*)ws;                        // 1 MB   (B*128 f32)
    _Float16*  tbuf = (_Float16*)(ws + (1 << 20));       // 0.5 MB (B*128 f16)
    _Float16*  h1   = (_Float16*)(ws + 2 * (1 << 20));   // 1 MB
    _Float16*  h2   = (_Float16*)(ws + 3 * (1 << 20));   // 1 MB

    ode_kernel<<<128, 512, 0, stream>>>(past, xproj_w, xproj_b, z0_w, z0_b,
                                        ln_g, ln_b, w1, b1, w2, b2, w3, b3, zbuf);

    temb_kernel<<<16, 256, 0, stream>>>(tvals, tbuf);

    gemm1d_kernel<<<dim3(32, 4), 256, 0, stream>>>(x_t, zbuf, tbuf, fw1, fb1, h1);

    gemm_f16<true,  true ><<<dim3(32, 4),  256, 0, stream>>>(h1, fw2, fb2, h2, 2048, 256, 256);
    gemm_f16<false, false><<<dim3(32, 48), 256, 0, stream>>>(h2, fw3, fb3, d_out, 2048, 3072, 256);
}

// Round 13
// 306.573 us; speedup vs baseline: 2.4535x; 1.1808x over previous
//
#include <hip/hip_runtime.h>
#include <math.h>

typedef _Float16 h8f16 __attribute__((ext_vector_type(8)));
typedef _Float16 h2f16 __attribute__((ext_vector_type(2)));
typedef float f32x4 __attribute__((ext_vector_type(4)));

#define MFMA16(a, b, c) __builtin_amdgcn_mfma_f32_16x16x32_f16((a), (b), (c), 0, 0, 0)

__device__ __forceinline__ float silu_f(float v) {
    return v * __builtin_amdgcn_rcpf(1.0f + __expf(-v));
}

// Bare barrier: writer-side LDS completion + s_barrier, NO vmcnt drain.
__device__ __forceinline__ void bar_lds() {
    asm volatile("s_waitcnt lgkmcnt(0)" ::: "memory");
    __builtin_amdgcn_s_barrier();
    __builtin_amdgcn_sched_barrier(0);
}

// ---------------------------------------------------------------------------
// ODE mega-kernel v6 (proven 258 us): 32 RK4 steps, bare barriers, fdot2 LN
// stats, gamma/beta folded, bx streamed from global (never vmcnt-drained).
// grid: 128 blocks (16 batch rows) x 512 threads (8 waves; wave w owns output
// cols [16w,16w+16)). z0 computed in the prologue (f32 exact).
// ---------------------------------------------------------------------------
__global__ __launch_bounds__(512, 1) void ode_kernel(
    const float* __restrict__ past,
    const float* __restrict__ xproj_w, const float* __restrict__ xproj_b,
    const float* __restrict__ z0_w, const float* __restrict__ z0_b,
    const float* __restrict__ ln_g, const float* __restrict__ ln_b,
    const float* __restrict__ w1, const float* __restrict__ b1,
    const float* __restrict__ w2, const float* __restrict__ b2,
    const float* __restrict__ w3, const float* __restrict__ b3,
    float* __restrict__ zbuf)
{
    __shared__ _Float16 hbuf[16][136];   // LN input v
    __shared__ _Float16 h1S[16][136];
    __shared__ _Float16 h2S[16][136];
    __shared__ float    pS[16][33];      // prologue stages
    __shared__ float    x0S[16][128];
    __shared__ float    zS0[16][129];

    const int tid  = threadIdx.x;
    const int wid  = tid >> 6;
    const int lane = tid & 63;
    const int lrow = lane & 15;
    const int lhi  = lane >> 4;
    const int b0   = blockIdx.x * 16;
    const int nc   = wid * 16 + lrow;    // this lane's output col (all layers)
    const int koff = lhi * 8;

    // ---- weights into register B-fragments; gamma folded into W1a ----
    h8f16 w1f[4], wcf, w2f[4], w3f[4];
    float b1t, b2r, b3r;
    {
#pragma unroll
        for (int ks = 0; ks < 4; ++ks) {
            h8f16 v1, v2, v3;
#pragma unroll
            for (int j = 0; j < 8; ++j) {
                const int k = ks * 32 + koff + j;
                v1[j] = (_Float16)(w1[nc * 256 + k] * ln_g[k]);
                v2[j] = (_Float16)w2[nc * 128 + k];
                v3[j] = (_Float16)w3[nc * 128 + k];
            }
            w1f[ks] = v1; w2f[ks] = v2; w3f[ks] = v3;
        }
        // Wc = W1b @ xproj_w ; bc = W1b @ xproj_b ; bb = W1a @ ln_b
        float wc[8] = {0, 0, 0, 0, 0, 0, 0, 0};
        float bc = 0.0f, bb = 0.0f;
        const float* w1a = w1 + nc * 256;
        const float* w1b = w1a + 128;
#pragma unroll 4
        for (int k = 0; k < 128; ++k) {
            const float a = w1b[k];
            bc += a * xproj_b[k];
            bb += w1a[k] * ln_b[k];
            const float* xr = xproj_w + k * 32 + koff;
#pragma unroll
            for (int j = 0; j < 8; ++j) wc[j] += a * xr[j];
        }
        h8f16 v;
#pragma unroll
        for (int j = 0; j < 8; ++j) v[j] = (_Float16)wc[j];
        wcf = v;
        b1t = b1[nc] + bc + bb;
        b2r = b2[nc]; b3r = b3[nc];
    }

    // ---- prologue: z0 = (past[:,0,:] @ xw.T + xb) @ z0w.T + z0b (f32) ----
    pS[tid >> 5][tid & 31] = past[(long)(b0 + (tid >> 5)) * 16384 + (tid & 31)];
    __syncthreads();
    {
        const int r  = tid >> 5;
        const int c0 = (tid & 31) * 4;
#pragma unroll
        for (int cc = 0; cc < 4; ++cc) {
            const int kc = c0 + cc;
            float s = xproj_b[kc];
            const float* xr = xproj_w + kc * 32;
#pragma unroll
            for (int c = 0; c < 32; ++c) s += pS[r][c] * xr[c];
            x0S[r][kc] = s;
        }
    }
    __syncthreads();
    {
        const int nn = tid & 127;
        const int r0 = (tid >> 7) * 4;
        for (int p = 0; p < 4; ++p) {
            const int r = r0 + p;
            float s = z0_b[nn];
            const float* zr = z0_w + nn * 128;
            for (int k = 0; k < 128; ++k) s += x0S[r][k] * zr[k];
            zS0[r][nn] = s;
        }
    }
    __syncthreads();

    // ---- z cached per-lane in C-frag layout (rows 4*lhi+j, col nc) ----
    float zc[4], krk[4];
#pragma unroll
    for (int j = 0; j < 4; ++j) {
        zc[j] = zS0[4 * lhi + j][nc];
        hbuf[4 * lhi + j][nc] = (_Float16)zc[j];
    }

    const float DT = 1.0f / 32.0f;

    // ---- bx streaming (global loads; never drained in-loop) ----
    f32x4 s0a, s0b, s1a, s1b;
    auto stage = [&](int e) {
        const float pos = (float)e * 7.984375f;   // e*(511/64), exact
        const int i0 = (int)pos;
        const int i1 = (i0 < 511) ? i0 + 1 : 511;
        const float* base = past + (long)(b0 + lrow) * 16384;
        const float* p0 = base + i0 * 32 + koff;
        const float* p1 = base + i1 * 32 + koff;
        s0a = *(const f32x4*)p0; s0b = *(const f32x4*)(p0 + 4);
        s1a = *(const f32x4*)p1; s1b = *(const f32x4*)(p1 + 4);
    };
    auto blend = [&](int e) -> h8f16 {
        const float pos = (float)e * 7.984375f;
        const float w = pos - floorf(pos);
        h8f16 r;
#pragma unroll
        for (int j = 0; j < 4; ++j) {
            r[j]     = (_Float16)(s0a[j] + w * (s1a[j] - s0a[j]));
            r[4 + j] = (_Float16)(s0b[j] + w * (s1b[j] - s0b[j]));
        }
        return r;
    };

    const h2f16 one2 = {(_Float16)1.0f, (_Float16)1.0f};

    auto phaseA = [&](h8f16 bxc) {
        h8f16 xf[4];
#pragma unroll
        for (int ks = 0; ks < 4; ++ks)
            xf[ks] = *(const h8f16*)&hbuf[lrow][ks * 32 + koff];
        // LN stats via v_dot2_f32_f16 (2 independent accumulator chains each)
        float s0 = 0.f, s1 = 0.f, q0 = 0.f, q1 = 0.f;
#pragma unroll
        for (int ks = 0; ks < 4; ++ks) {
#pragma unroll
            for (int p = 0; p < 4; ++p) {
                const h2f16 x2 = {xf[ks][2 * p], xf[ks][2 * p + 1]};
                if (p & 1) {
                    s1 = __builtin_amdgcn_fdot2(x2, one2, s1, false);
                    q1 = __builtin_amdgcn_fdot2(x2, x2, q1, false);
                } else {
                    s0 = __builtin_amdgcn_fdot2(x2, one2, s0, false);
                    q0 = __builtin_amdgcn_fdot2(x2, x2, q0, false);
                }
            }
        }
        float s = s0 + s1, q = q0 + q1;
        s += __shfl_xor(s, 16); q += __shfl_xor(q, 16);
        s += __shfl_xor(s, 32); q += __shfl_xor(q, 32);
        const float mu  = s * (1.0f / 128.0f);
        const float var = q * (1.0f / 128.0f) - mu * mu;
        const float inv = 1.0f / sqrtf(var + 1e-5f);
        const _Float16 ih = (_Float16)inv;
        const _Float16 mh = (_Float16)(-mu * inv);
        h8f16 ip, mp;
#pragma unroll
        for (int j = 0; j < 8; ++j) { ip[j] = ih; mp[j] = mh; }
        f32x4 acc = {0, 0, 0, 0};
#pragma unroll
        for (int ks = 0; ks < 4; ++ks) {
            const h8f16 az = xf[ks] * ip + mp;   // packed f16 LN-apply (γ,β folded)
            acc = MFMA16(az, w1f[ks], acc);
        }
        acc = MFMA16(bxc, wcf, acc);
#pragma unroll
        for (int j = 0; j < 4; ++j)
            h1S[4 * lhi + j][nc] = (_Float16)silu_f(acc[j] + b1t);
    };
    auto phaseB = [&]() {
        f32x4 acc = {0, 0, 0, 0};
#pragma unroll
        for (int ks = 0; ks < 4; ++ks) {
            const h8f16 a = *(const h8f16*)&h1S[lrow][ks * 32 + koff];
            acc = MFMA16(a, w2f[ks], acc);
        }
#pragma unroll
        for (int j = 0; j < 4; ++j)
            h2S[4 * lhi + j][nc] = (_Float16)silu_f(acc[j] + b2r);
    };
    auto phaseC = [&]() -> f32x4 {
        f32x4 acc = {0, 0, 0, 0};
#pragma unroll
        for (int ks = 0; ks < 4; ++ks) {
            const h8f16 a = *(const h8f16*)&h2S[lrow][ks * 32 + koff];
            acc = MFMA16(a, w3f[ks], acc);
        }
#pragma unroll
        for (int j = 0; j < 4; ++j) acc[j] += b3r;
        return acc;
    };

    stage(0);
    h8f16 bxc = blend(0);
    __syncthreads();

#pragma unroll 1
    for (int st = 0; st < 32; ++st) {
        const int e1 = 2 * st + 1, e2 = 2 * st + 2;
        // ---- sub0: k1 ----
        phaseA(bxc);
        stage(e1);                                   // prefetch tile e1 (stays in flight)
        bar_lds();
        phaseB(); bar_lds();
        {
            const f32x4 k = phaseC();
#pragma unroll
            for (int j = 0; j < 4; ++j) {
                krk[j] = k[j];
                hbuf[4 * lhi + j][nc] = (_Float16)(zc[j] + 0.5f * DT * k[j]);
            }
        }
        bar_lds();
        // ---- sub1: k2 ----
        bxc = blend(e1);
        phaseA(bxc); bar_lds();
        phaseB(); bar_lds();
        {
            const f32x4 k = phaseC();
#pragma unroll
            for (int j = 0; j < 4; ++j) {
                krk[j] += 2.0f * k[j];
                hbuf[4 * lhi + j][nc] = (_Float16)(zc[j] + 0.5f * DT * k[j]);
            }
        }
        bar_lds();
        // ---- sub2: k3 ----
        phaseA(bxc);
        stage(e2);                                   // prefetch tile e2
        bar_lds();
        phaseB(); bar_lds();
        {
            const f32x4 k = phaseC();
#pragma unroll
            for (int j = 0; j < 4; ++j) {
                krk[j] += 2.0f * k[j];
                hbuf[4 * lhi + j][nc] = (_Float16)(zc[j] + DT * k[j]);
            }
        }
        bar_lds();
        // ---- sub3: k4 + z update ----
        bxc = blend(e2);
        phaseA(bxc); bar_lds();
        phaseB(); bar_lds();
        {
            const f32x4 k = phaseC();
#pragma unroll
            for (int j = 0; j < 4; ++j) {
                zc[j] += (DT / 6.0f) * (krk[j] + k[j]);
                hbuf[4 * lhi + j][nc] = (_Float16)zc[j];
            }
        }
        bar_lds();
    }

#pragma unroll
    for (int j = 0; j < 4; ++j)
        zbuf[(long)(b0 + 4 * lhi + j) * 128 + nc] = zc[j];
}

// ---------------------------------------------------------------------------
// hcatw: blocks < 3328 build hcat = [x_t|cond|temb] f16 (round-6 proven);
//        blocks >= 3328 convert fw1/fw2/fw3 f32 -> f16 (212992 chunks of 8).
// ---------------------------------------------------------------------------
__global__ __launch_bounds__(256) void hcatw_kernel(
    const float* __restrict__ x_t, const float* __restrict__ cond,
    const int* __restrict__ tvals, _Float16* __restrict__ hcat,
    const float* __restrict__ fw1, const float* __restrict__ fw2,
    const float* __restrict__ fw3,
    _Float16* __restrict__ fw1h, _Float16* __restrict__ fw2h,
    _Float16* __restrict__ fw3h)
{
    const int tid = threadIdx.x;
    if (blockIdx.x >= 3328) {
        const int c = (blockIdx.x - 3328) * 256 + tid;   // chunk of 8 elems
        const float* src; _Float16* dst; long off;
        if (c < 106496)      { src = fw1; dst = fw1h; off = (long)c * 8; }
        else if (c < 114688) { src = fw2; dst = fw2h; off = (long)(c - 106496) * 8; }
        else                 { src = fw3; dst = fw3h; off = (long)(c - 114688) * 8; }
        const f32x4 u0 = *(const f32x4*)(src + off);
        const f32x4 u1 = *(const f32x4*)(src + off + 4);
        h8f16 v;
#pragma unroll
        for (int j = 0; j < 4; ++j) { v[j] = (_Float16)u0[j]; v[4 + j] = (_Float16)u1[j]; }
        *(h8f16*)&dst[off] = v;
        return;
    }
    const int gid = blockIdx.x * 256 + tid;
    const int b  = gid / 416;
    const int j0 = (gid % 416) * 8;
    h8f16 v;
    if (j0 < 3072) {
        const float* s = x_t + (long)b * 3072 + j0;
#pragma unroll
        for (int j = 0; j < 8; ++j) v[j] = (_Float16)s[j];
    } else if (j0 < 3200) {
        const float* s = cond + (long)b * 128 + (j0 - 3072);
#pragma unroll
        for (int j = 0; j < 8; ++j) v[j] = (_Float16)s[j];
    } else {
        const float tv = (float)tvals[b];
#pragma unroll
        for (int j = 0; j < 8; ++j) {
            const int jj  = j0 - 3200 + j;
            const int idx = (jj < 64) ? jj : jj - 64;
            const float fr = expf(-9.210340371976184f * (float)idx * (1.0f / 63.0f));
            const float a  = tv * fr;
            v[j] = (_Float16)((jj < 64) ? sinf(a) : cosf(a));
        }
    }
    *(h8f16*)&hcat[(long)b * 3328 + j0] = v;
}

// ---------------------------------------------------------------------------
// Generic all-f16 MFMA GEMM: out(M,N) = [silu](A(M,K) @ W(N,K).T + bias)
// A f16, W f16 (pre-converted), bias f32. Tile 64x64, K-step 32.
// ---------------------------------------------------------------------------
template <bool SILU, bool OUT_F16>
__global__ __launch_bounds__(256) void gemm_ff(
    const _Float16* __restrict__ A, const _Float16* __restrict__ W,
    const float* __restrict__ bias, void* __restrict__ out,
    int M, int N, int K)
{
    __shared__ _Float16 aS[64][40];
    __shared__ _Float16 wS[64][40];
    const int mb = blockIdx.x * 64, nb = blockIdx.y * 64;
    const int tid = threadIdx.x, lane = tid & 63, wq = tid >> 6;
    const int lrow = lane & 15, lhi = lane >> 4;
    f32x4 acc[4];
#pragma unroll
    for (int nt = 0; nt < 4; ++nt) acc[nt] = (f32x4){0, 0, 0, 0};

    const int sr = tid >> 2;
    const int sk = (tid & 3) * 8;

    for (int k0 = 0; k0 < K; k0 += 32) {
        *(h8f16*)&aS[sr][sk] = *(const h8f16*)&A[(long)(mb + sr) * K + k0 + sk];
        *(h8f16*)&wS[sr][sk] = *(const h8f16*)&W[(long)(nb + sr) * K + k0 + sk];
        __syncthreads();
        const h8f16 a = *(const h8f16*)&aS[wq * 16 + lrow][lhi * 8];
#pragma unroll
        for (int nt = 0; nt < 4; ++nt) {
            const h8f16 bfr = *(const h8f16*)&wS[nt * 16 + lrow][lhi * 8];
            acc[nt] = MFMA16(a, bfr, acc[nt]);
        }
        __syncthreads();
    }

#pragma unroll
    for (int nt = 0; nt < 4; ++nt) {
        const int cc = nb + nt * 16 + lrow;
        const float bv = bias[cc];
#pragma unroll
        for (int j = 0; j < 4; ++j) {
            const int rr = mb + wq * 16 + lhi * 4 + j;
            float v = acc[nt][j] + bv;
            if (SILU) v = silu_f(v);
            if (OUT_F16) ((_Float16*)out)[(long)rr * N + cc] = (_Float16)v;
            else         ((float*)out)[(long)rr * N + cc] = v;
        }
    }
}

// ---------------------------------------------------------------------------
extern "C" void kernel_launch(void* const* d_in, const int* in_sizes, int n_in,
                              void* d_out, int out_size, void* d_ws, size_t ws_size,
                              hipStream_t stream)
{
    const float* x_t     = (const float*)d_in[0];
    const float* past    = (const float*)d_in[1];
    const int*   tvals   = (const int*)d_in[2];
    const float* xproj_w = (const float*)d_in[3];
    const float* xproj_b = (const float*)d_in[4];
    const float* z0_w    = (const float*)d_in[5];
    const float* z0_b    = (const float*)d_in[6];
    const float* ln_g    = (const float*)d_in[7];
    const float* ln_b    = (const float*)d_in[8];
    const float* w1      = (const float*)d_in[9];
    const float* b1      = (const float*)d_in[10];
    const float* w2      = (const float*)d_in[11];
    const float* b2      = (const float*)d_in[12];
    const float* w3      = (const float*)d_in[13];
    const float* b3      = (const float*)d_in[14];
    const float* fw1     = (const float*)d_in[15];
    const float* fb1     = (const float*)d_in[16];
    const float* fw2     = (const float*)d_in[17];
    const float* fb2     = (const float*)d_in[18];
    const float* fw3     = (const float*)d_in[19];
    const float* fb3     = (const float*)d_in[20];

    char* ws = (char*)d_ws;
    float*     zbuf = (float*)ws;                         // 1 MB   (B*128 f32)
    _Float16*  hcat = (_Float16*)(ws + (1 << 20));        // 13.63 MB
    _Float16*  h1   = (_Float16*)(ws + 15 * (1 << 20));   // 1 MB
    _Float16*  h2   = (_Float16*)(ws + 16 * (1 << 20));   // 1 MB
    _Float16*  fw1h = (_Float16*)(ws + 17 * (1 << 20));   // 1.70 MB (256x3328)
    _Float16*  fw2h = (_Float16*)(ws + 19 * (1 << 20));   // 0.13 MB (256x256)
    _Float16*  fw3h = (_Float16*)(ws + 20 * (1 << 20));   // 1.57 MB (3072x256)

    ode_kernel<<<128, 512, 0, stream>>>(past, xproj_w, xproj_b, z0_w, z0_b,
                                        ln_g, ln_b, w1, b1, w2, b2, w3, b3, zbuf);

    hcatw_kernel<<<3328 + 832, 256, 0, stream>>>(x_t, zbuf, tvals, hcat,
                                                 fw1, fw2, fw3, fw1h, fw2h, fw3h);

    gemm_ff<true,  true ><<<dim3(32, 4),  256, 0, stream>>>(hcat, fw1h, fb1, h1, 2048, 256, 3328);
    gemm_ff<true,  true ><<<dim3(32, 4),  256, 0, stream>>>(h1,   fw2h, fb2, h2, 2048, 256, 256);
    gemm_ff<false, false><<<dim3(32, 48), 256, 0, stream>>>(h2,   fw3h, fb3, d_out, 2048, 3072, 256);
}

// Round 14
// 297.828 us; speedup vs baseline: 2.5256x; 1.0294x over previous
//
#include <hip/hip_runtime.h>
#include <math.h>

typedef _Float16 h8f16 __attribute__((ext_vector_type(8)));
typedef _Float16 h2f16 __attribute__((ext_vector_type(2)));
typedef float f32x4 __attribute__((ext_vector_type(4)));

#define MFMA16(a, b, c) __builtin_amdgcn_mfma_f32_16x16x32_f16((a), (b), (c), 0, 0, 0)

__device__ __forceinline__ float silu_f(float v) {
    return v * __builtin_amdgcn_rcpf(1.0f + __expf(-v));
}

// Bare barrier: writer-side LDS completion + s_barrier, NO vmcnt drain.
__device__ __forceinline__ void bar_lds() {
    asm volatile("s_waitcnt lgkmcnt(0)" ::: "memory");
    __builtin_amdgcn_s_barrier();
    __builtin_amdgcn_sched_barrier(0);
}

// ---------------------------------------------------------------------------
// FAT kernel, 232 blocks x 512 threads:
//   blocks 0..127   : ODE mega-kernel (v6, verbatim — proven 258 us)
//   blocks 128..231 : pure-STREAMING filler (grid-stride): hcat x_t cols,
//                     temb cols, fw1/fw2/fw3 f32->f16 conversion (~42 MB).
//                     No MFMA, no L2-reuse loop -> bounded interference
//                     (round-10's regression came from the fused GEMM).
// cond columns of hcat are NOT written here; gemm1z stages them from zbuf.
// ---------------------------------------------------------------------------
__global__ __launch_bounds__(512, 1) void fat_kernel(
    const float* __restrict__ past,
    const float* __restrict__ xproj_w, const float* __restrict__ xproj_b,
    const float* __restrict__ z0_w, const float* __restrict__ z0_b,
    const float* __restrict__ ln_g, const float* __restrict__ ln_b,
    const float* __restrict__ w1, const float* __restrict__ b1,
    const float* __restrict__ w2, const float* __restrict__ b2,
    const float* __restrict__ w3, const float* __restrict__ b3,
    const float* __restrict__ x_t, const int* __restrict__ tvals,
    const float* __restrict__ fw1, const float* __restrict__ fw2,
    const float* __restrict__ fw3,
    float* __restrict__ zbuf, _Float16* __restrict__ hcat,
    _Float16* __restrict__ fw1h, _Float16* __restrict__ fw2h,
    _Float16* __restrict__ fw3h)
{
    __shared__ _Float16 hbuf[16][136];   // (ODE path only)
    __shared__ _Float16 h1S[16][136];
    __shared__ _Float16 h2S[16][136];
    __shared__ float    pS[16][33];
    __shared__ float    x0S[16][128];
    __shared__ float    zS0[16][129];

    const int tid = threadIdx.x;

    if (blockIdx.x >= 128) {
        // ================= streaming filler path =================
        // work items (chunks of 8 elems):
        //   [0, 786432)            hcat x_t cols  (2048 x 3072 /8)
        //   [786432, 819200)       hcat temb cols (2048 x 128 /8)
        //   [819200, 925696)       fw1h           (256 x 3328 /8)
        //   [925696, 933888)       fw2h           (256 x 256 /8)
        //   [933888, 1032192)      fw3h           (3072 x 256 /8)
        const int fid = blockIdx.x - 128;          // 0..103
        for (long c = fid * 512 + tid; c < 1032192; c += 104 * 512) {
            if (c < 786432) {
                const long b = c / 384, q = (c % 384) * 8;
                const float* s = x_t + b * 3072 + q;
                const f32x4 u0 = *(const f32x4*)s;
                const f32x4 u1 = *(const f32x4*)(s + 4);
                h8f16 v;
#pragma unroll
                for (int j = 0; j < 4; ++j) { v[j] = (_Float16)u0[j]; v[4 + j] = (_Float16)u1[j]; }
                *(h8f16*)&hcat[b * 3328 + q] = v;
            } else if (c < 819200) {
                const long u = c - 786432;
                const long b = u >> 4;
                const int j0 = (int)(u & 15) * 8;
                const float tv = (float)tvals[b];
                h8f16 v;
#pragma unroll
                for (int j = 0; j < 8; ++j) {
                    const int jj  = j0 + j;
                    const int idx = (jj < 64) ? jj : jj - 64;
                    const float fr = expf(-9.210340371976184f * (float)idx * (1.0f / 63.0f));
                    const float a  = tv * fr;
                    v[j] = (_Float16)((jj < 64) ? sinf(a) : cosf(a));
                }
                *(h8f16*)&hcat[b * 3328 + 3200 + j0] = v;
            } else {
                const float* src; _Float16* dst; long off;
                if (c < 925696)      { src = fw1; dst = fw1h; off = (c - 819200) * 8; }
                else if (c < 933888) { src = fw2; dst = fw2h; off = (c - 925696) * 8; }
                else                 { src = fw3; dst = fw3h; off = (c - 933888) * 8; }
                const f32x4 u0 = *(const f32x4*)(src + off);
                const f32x4 u1 = *(const f32x4*)(src + off + 4);
                h8f16 v;
#pragma unroll
                for (int j = 0; j < 4; ++j) { v[j] = (_Float16)u0[j]; v[4 + j] = (_Float16)u1[j]; }
                *(h8f16*)&dst[off] = v;
            }
        }
        return;
    }

    // ===================== ODE path (v6, verbatim) =====================
    const int wid  = tid >> 6;
    const int lane = tid & 63;
    const int lrow = lane & 15;
    const int lhi  = lane >> 4;
    const int b0   = blockIdx.x * 16;
    const int nc   = wid * 16 + lrow;
    const int koff = lhi * 8;

    // ---- weights into register B-fragments; gamma folded into W1a ----
    h8f16 w1f[4], wcf, w2f[4], w3f[4];
    float b1t, b2r, b3r;
    {
#pragma unroll
        for (int ks = 0; ks < 4; ++ks) {
            h8f16 v1, v2, v3;
#pragma unroll
            for (int j = 0; j < 8; ++j) {
                const int k = ks * 32 + koff + j;
                v1[j] = (_Float16)(w1[nc * 256 + k] * ln_g[k]);
                v2[j] = (_Float16)w2[nc * 128 + k];
                v3[j] = (_Float16)w3[nc * 128 + k];
            }
            w1f[ks] = v1; w2f[ks] = v2; w3f[ks] = v3;
        }
        float wc[8] = {0, 0, 0, 0, 0, 0, 0, 0};
        float bc = 0.0f, bb = 0.0f;
        const float* w1a = w1 + nc * 256;
        const float* w1b = w1a + 128;
#pragma unroll 4
        for (int k = 0; k < 128; ++k) {
            const float a = w1b[k];
            bc += a * xproj_b[k];
            bb += w1a[k] * ln_b[k];
            const float* xr = xproj_w + k * 32 + koff;
#pragma unroll
            for (int j = 0; j < 8; ++j) wc[j] += a * xr[j];
        }
        h8f16 v;
#pragma unroll
        for (int j = 0; j < 8; ++j) v[j] = (_Float16)wc[j];
        wcf = v;
        b1t = b1[nc] + bc + bb;
        b2r = b2[nc]; b3r = b3[nc];
    }

    // ---- prologue: z0 = (past[:,0,:] @ xw.T + xb) @ z0w.T + z0b (f32) ----
    pS[tid >> 5][tid & 31] = past[(long)(b0 + (tid >> 5)) * 16384 + (tid & 31)];
    __syncthreads();
    {
        const int r  = tid >> 5;
        const int c0 = (tid & 31) * 4;
#pragma unroll
        for (int cc = 0; cc < 4; ++cc) {
            const int kc = c0 + cc;
            float s = xproj_b[kc];
            const float* xr = xproj_w + kc * 32;
#pragma unroll
            for (int c = 0; c < 32; ++c) s += pS[r][c] * xr[c];
            x0S[r][kc] = s;
        }
    }
    __syncthreads();
    {
        const int nn = tid & 127;
        const int r0 = (tid >> 7) * 4;
        for (int p = 0; p < 4; ++p) {
            const int r = r0 + p;
            float s = z0_b[nn];
            const float* zr = z0_w + nn * 128;
            for (int k = 0; k < 128; ++k) s += x0S[r][k] * zr[k];
            zS0[r][nn] = s;
        }
    }
    __syncthreads();

    float zc[4], krk[4];
#pragma unroll
    for (int j = 0; j < 4; ++j) {
        zc[j] = zS0[4 * lhi + j][nc];
        hbuf[4 * lhi + j][nc] = (_Float16)zc[j];
    }

    const float DT = 1.0f / 32.0f;

    f32x4 s0a, s0b, s1a, s1b;
    auto stage = [&](int e) {
        const float pos = (float)e * 7.984375f;   // e*(511/64), exact
        const int i0 = (int)pos;
        const int i1 = (i0 < 511) ? i0 + 1 : 511;
        const float* base = past + (long)(b0 + lrow) * 16384;
        const float* p0 = base + i0 * 32 + koff;
        const float* p1 = base + i1 * 32 + koff;
        s0a = *(const f32x4*)p0; s0b = *(const f32x4*)(p0 + 4);
        s1a = *(const f32x4*)p1; s1b = *(const f32x4*)(p1 + 4);
    };
    auto blend = [&](int e) -> h8f16 {
        const float pos = (float)e * 7.984375f;
        const float w = pos - floorf(pos);
        h8f16 r;
#pragma unroll
        for (int j = 0; j < 4; ++j) {
            r[j]     = (_Float16)(s0a[j] + w * (s1a[j] - s0a[j]));
            r[4 + j] = (_Float16)(s0b[j] + w * (s1b[j] - s0b[j]));
        }
        return r;
    };

    const h2f16 one2 = {(_Float16)1.0f, (_Float16)1.0f};

    auto phaseA = [&](h8f16 bxc) {
        h8f16 xf[4];
#pragma unroll
        for (int ks = 0; ks < 4; ++ks)
            xf[ks] = *(const h8f16*)&hbuf[lrow][ks * 32 + koff];
        float s0 = 0.f, s1 = 0.f, q0 = 0.f, q1 = 0.f;
#pragma unroll
        for (int ks = 0; ks < 4; ++ks) {
#pragma unroll
            for (int p = 0; p < 4; ++p) {
                const h2f16 x2 = {xf[ks][2 * p], xf[ks][2 * p + 1]};
                if (p & 1) {
                    s1 = __builtin_amdgcn_fdot2(x2, one2, s1, false);
                    q1 = __builtin_amdgcn_fdot2(x2, x2, q1, false);
                } else {
                    s0 = __builtin_amdgcn_fdot2(x2, one2, s0, false);
                    q0 = __builtin_amdgcn_fdot2(x2, x2, q0, false);
                }
            }
        }
        float s = s0 + s1, q = q0 + q1;
        s += __shfl_xor(s, 16); q += __shfl_xor(q, 16);
        s += __shfl_xor(s, 32); q += __shfl_xor(q, 32);
        const float mu  = s * (1.0f / 128.0f);
        const float var = q * (1.0f / 128.0f) - mu * mu;
        const float inv = 1.0f / sqrtf(var + 1e-5f);
        const _Float16 ih = (_Float16)inv;
        const _Float16 mh = (_Float16)(-mu * inv);
        h8f16 ip, mp;
#pragma unroll
        for (int j = 0; j < 8; ++j) { ip[j] = ih; mp[j] = mh; }
        f32x4 acc = {0, 0, 0, 0};
#pragma unroll
        for (int ks = 0; ks < 4; ++ks) {
            const h8f16 az = xf[ks] * ip + mp;
            acc = MFMA16(az, w1f[ks], acc);
        }
        acc = MFMA16(bxc, wcf, acc);
#pragma unroll
        for (int j = 0; j < 4; ++j)
            h1S[4 * lhi + j][nc] = (_Float16)silu_f(acc[j] + b1t);
    };
    auto phaseB = [&]() {
        f32x4 acc = {0, 0, 0, 0};
#pragma unroll
        for (int ks = 0; ks < 4; ++ks) {
            const h8f16 a = *(const h8f16*)&h1S[lrow][ks * 32 + koff];
            acc = MFMA16(a, w2f[ks], acc);
        }
#pragma unroll
        for (int j = 0; j < 4; ++j)
            h2S[4 * lhi + j][nc] = (_Float16)silu_f(acc[j] + b2r);
    };
    auto phaseC = [&]() -> f32x4 {
        f32x4 acc = {0, 0, 0, 0};
#pragma unroll
        for (int ks = 0; ks < 4; ++ks) {
            const h8f16 a = *(const h8f16*)&h2S[lrow][ks * 32 + koff];
            acc = MFMA16(a, w3f[ks], acc);
        }
#pragma unroll
        for (int j = 0; j < 4; ++j) acc[j] += b3r;
        return acc;
    };

    stage(0);
    h8f16 bxc = blend(0);
    __syncthreads();

#pragma unroll 1
    for (int st = 0; st < 32; ++st) {
        const int e1 = 2 * st + 1, e2 = 2 * st + 2;
        // ---- sub0: k1 ----
        phaseA(bxc);
        stage(e1);
        bar_lds();
        phaseB(); bar_lds();
        {
            const f32x4 k = phaseC();
#pragma unroll
            for (int j = 0; j < 4; ++j) {
                krk[j] = k[j];
                hbuf[4 * lhi + j][nc] = (_Float16)(zc[j] + 0.5f * DT * k[j]);
            }
        }
        bar_lds();
        // ---- sub1: k2 ----
        bxc = blend(e1);
        phaseA(bxc); bar_lds();
        phaseB(); bar_lds();
        {
            const f32x4 k = phaseC();
#pragma unroll
            for (int j = 0; j < 4; ++j) {
                krk[j] += 2.0f * k[j];
                hbuf[4 * lhi + j][nc] = (_Float16)(zc[j] + 0.5f * DT * k[j]);
            }
        }
        bar_lds();
        // ---- sub2: k3 ----
        phaseA(bxc);
        stage(e2);
        bar_lds();
        phaseB(); bar_lds();
        {
            const f32x4 k = phaseC();
#pragma unroll
            for (int j = 0; j < 4; ++j) {
                krk[j] += 2.0f * k[j];
                hbuf[4 * lhi + j][nc] = (_Float16)(zc[j] + DT * k[j]);
            }
        }
        bar_lds();
        // ---- sub3: k4 + z update ----
        bxc = blend(e2);
        phaseA(bxc); bar_lds();
        phaseB(); bar_lds();
        {
            const f32x4 k = phaseC();
#pragma unroll
            for (int j = 0; j < 4; ++j) {
                zc[j] += (DT / 6.0f) * (krk[j] + k[j]);
                hbuf[4 * lhi + j][nc] = (_Float16)zc[j];
            }
        }
        bar_lds();
    }

#pragma unroll
    for (int j = 0; j < 4; ++j)
        zbuf[(long)(b0 + 4 * lhi + j) * 128 + nc] = zc[j];
}

// ---------------------------------------------------------------------------
// gemm1z: h1 = silu([hcat_xt | cond(zbuf,f32) | hcat_temb] @ fw1h.T + fb1)
// M=2048 N=256 K=3328; cond cols (3072..3199) staged from zbuf f32->f16
// (bitwise-identical to the hcat path). grid (32,4) x 256 threads.
// ---------------------------------------------------------------------------
__global__ __launch_bounds__(256) void gemm1z_kernel(
    const _Float16* __restrict__ hcat, const float* __restrict__ cond,
    const _Float16* __restrict__ fw1h, const float* __restrict__ fb1,
    _Float16* __restrict__ h1)
{
    __shared__ _Float16 aS[64][40];
    __shared__ _Float16 wS[64][40];
    const int mb = blockIdx.x * 64, nb = blockIdx.y * 64;
    const int tid = threadIdx.x, lane = tid & 63, wq = tid >> 6;
    const int lrow = lane & 15, lhi = lane >> 4;
    f32x4 acc[4];
#pragma unroll
    for (int nt = 0; nt < 4; ++nt) acc[nt] = (f32x4){0, 0, 0, 0};

    const int sr = tid >> 2;
    const int sk = (tid & 3) * 8;

    for (int k0 = 0; k0 < 3328; k0 += 32) {
        if (k0 >= 3072 && k0 < 3200) {
            const float* s = cond + (long)(mb + sr) * 128 + (k0 - 3072) + sk;
            const f32x4 u0 = *(const f32x4*)s;
            const f32x4 u1 = *(const f32x4*)(s + 4);
            h8f16 v;
#pragma unroll
            for (int j = 0; j < 4; ++j) { v[j] = (_Float16)u0[j]; v[4 + j] = (_Float16)u1[j]; }
            *(h8f16*)&aS[sr][sk] = v;
        } else {
            *(h8f16*)&aS[sr][sk] =
                *(const h8f16*)&hcat[(long)(mb + sr) * 3328 + k0 + sk];
        }
        *(h8f16*)&wS[sr][sk] = *(const h8f16*)&fw1h[(long)(nb + sr) * 3328 + k0 + sk];
        __syncthreads();
        const h8f16 a = *(const h8f16*)&aS[wq * 16 + lrow][lhi * 8];
#pragma unroll
        for (int nt = 0; nt < 4; ++nt) {
            const h8f16 bfr = *(const h8f16*)&wS[nt * 16 + lrow][lhi * 8];
            acc[nt] = MFMA16(a, bfr, acc[nt]);
        }
        __syncthreads();
    }

#pragma unroll
    for (int nt = 0; nt < 4; ++nt) {
        const int cc = nb + nt * 16 + lrow;
        const float bv = fb1[cc];
#pragma unroll
        for (int j = 0; j < 4; ++j) {
            const int rr = mb + wq * 16 + lhi * 4 + j;
            h1[(long)rr * 256 + cc] = (_Float16)silu_f(acc[nt][j] + bv);
        }
    }
}

// ---------------------------------------------------------------------------
// Generic all-f16 MFMA GEMM: out(M,N) = [silu](A(M,K) @ W(N,K).T + bias)
// ---------------------------------------------------------------------------
template <bool SILU, bool OUT_F16>
__global__ __launch_bounds__(256) void gemm_ff(
    const _Float16* __restrict__ A, const _Float16* __restrict__ W,
    const float* __restrict__ bias, void* __restrict__ out,
    int M, int N, int K)
{
    __shared__ _Float16 aS[64][40];
    __shared__ _Float16 wS[64][40];
    const int mb = blockIdx.x * 64, nb = blockIdx.y * 64;
    const int tid = threadIdx.x, lane = tid & 63, wq = tid >> 6;
    const int lrow = lane & 15, lhi = lane >> 4;
    f32x4 acc[4];
#pragma unroll
    for (int nt = 0; nt < 4; ++nt) acc[nt] = (f32x4){0, 0, 0, 0};

    const int sr = tid >> 2;
    const int sk = (tid & 3) * 8;

    for (int k0 = 0; k0 < K; k0 += 32) {
        *(h8f16*)&aS[sr][sk] = *(const h8f16*)&A[(long)(mb + sr) * K + k0 + sk];
        *(h8f16*)&wS[sr][sk] = *(const h8f16*)&W[(long)(nb + sr) * K + k0 + sk];
        __syncthreads();
        const h8f16 a = *(const h8f16*)&aS[wq * 16 + lrow][lhi * 8];
#pragma unroll
        for (int nt = 0; nt < 4; ++nt) {
            const h8f16 bfr = *(const h8f16*)&wS[nt * 16 + lrow][lhi * 8];
            acc[nt] = MFMA16(a, bfr, acc[nt]);
        }
        __syncthreads();
    }

#pragma unroll
    for (int nt = 0; nt < 4; ++nt) {
        const int cc = nb + nt * 16 + lrow;
        const float bv = bias[cc];
#pragma unroll
        for (int j = 0; j < 4; ++j) {
            const int rr = mb + wq * 16 + lhi * 4 + j;
            float v = acc[nt][j] + bv;
            if (SILU) v = silu_f(v);
            if (OUT_F16) ((_Float16*)out)[(long)rr * N + cc] = (_Float16)v;
            else         ((float*)out)[(long)rr * N + cc] = v;
        }
    }
}

// ---------------------------------------------------------------------------
extern "C" void kernel_launch(void* const* d_in, const int* in_sizes, int n_in,
                              void* d_out, int out_size, void* d_ws, size_t ws_size,
                              hipStream_t stream)
{
    const float* x_t     = (const float*)d_in[0];
    const float* past    = (const float*)d_in[1];
    const int*   tvals   = (const int*)d_in[2];
    const float* xproj_w = (const float*)d_in[3];
    const float* xproj_b = (const float*)d_in[4];
    const float* z0_w    = (const float*)d_in[5];
    const float* z0_b    = (const float*)d_in[6];
    const float* ln_g    = (const float*)d_in[7];
    const float* ln_b    = (const float*)d_in[8];
    const float* w1      = (const float*)d_in[9];
    const float* b1      = (const float*)d_in[10];
    const float* w2      = (const float*)d_in[11];
    const float* b2      = (const float*)d_in[12];
    const float* w3      = (const float*)d_in[13];
    const float* b3      = (const float*)d_in[14];
    const float* fw1     = (const float*)d_in[15];
    const float* fb1     = (const float*)d_in[16];
    const float* fw2     = (const float*)d_in[17];
    const float* fb2     = (const float*)d_in[18];
    const float* fw3     = (const float*)d_in[19];
    const float* fb3     = (const float*)d_in[20];

    char* ws = (char*)d_ws;
    float*     zbuf = (float*)ws;                         // 1 MB   (B*128 f32)
    _Float16*  hcat = (_Float16*)(ws + (1 << 20));        // 13.63 MB
    _Float16*  h1   = (_Float16*)(ws + 15 * (1 << 20));   // 1 MB
    _Float16*  h2   = (_Float16*)(ws + 16 * (1 << 20));   // 1 MB
    _Float16*  fw1h = (_Float16*)(ws + 17 * (1 << 20));   // 1.70 MB (256x3328)
    _Float16*  fw2h = (_Float16*)(ws + 19 * (1 << 20));   // 0.13 MB (256x256)
    _Float16*  fw3h = (_Float16*)(ws + 20 * (1 << 20));   // 1.57 MB (3072x256)

    fat_kernel<<<232, 512, 0, stream>>>(past, xproj_w, xproj_b, z0_w, z0_b,
                                        ln_g, ln_b, w1, b1, w2, b2, w3, b3,
                                        x_t, tvals, fw1, fw2, fw3,
                                        zbuf, hcat, fw1h, fw2h, fw3h);

    gemm1z_kernel<<<dim3(32, 4), 256, 0, stream>>>(hcat, zbuf, fw1h, fb1, h1);

    gemm_ff<true,  true ><<<dim3(32, 4),  256, 0, stream>>>(h1, fw2h, fb2, h2, 2048, 256, 256);
    gemm_ff<false, false><<<dim3(32, 48), 256, 0, stream>>>(h2, fw3h, fb3, d_out, 2048, 3072, 256);
}